// Round 3
// baseline (599.314 us; speedup 1.0000x reference)
//
#include <hip/hip_runtime.h>
#include <math.h>

#define C 100
#define NBINS 15
#define ROWS 64            // rows per wave-tile
#define RSTRIDE 103        // padded floats per row; odd (103%32=7) -> conflict-free LDS reads
#define WPB 2              // waves per block
#define TPB (WPB * 64)

// Pass 1: each WAVE independently stages a 64-row tile (coalesced float4 ->
// LDS, odd stride), then lane r reduces row r serially from LDS.
// Zero cross-lane shuffles (R2 was LDS-pipe-bound on ds_bpermute butterflies).
__global__ __launch_bounds__(TPB) void ece_pass1(
    const float* __restrict__ probs, const int* __restrict__ labels,
    float* __restrict__ partials, int N, int G) {
  __shared__ float tile[WPB][ROWS * RSTRIDE];   // 2*64*103*4 = 52,736 B
  __shared__ float sbin[2 * NBINS];             // [0..14]=sum conf, [15..29]=sum corr
  if (threadIdx.x < 2 * NBINS) sbin[threadIdx.x] = 0.0f;
  __syncthreads();

  const int  lane   = threadIdx.x & 63;
  const int  w      = threadIdx.x >> 6;
  const int  gw     = blockIdx.x * WPB + w;       // global wave id
  const int  numW   = G * WPB;
  const int  nTiles = (N + ROWS - 1) / ROWS;      // 1M/64 = 15625 exact
  const long totalF4 = ((long)N * C) / 4;
  float* my = tile[w];

  for (int t = gw; t < nTiles; t += numW) {
    // ---- stage: 1600 float4 per tile, fully coalesced; write to padded LDS.
    // float4 q = k*64+lane -> row = q/25, col4 = q%25.  q+=64 => row+=2,
    // col4+=14 (64 = 2*25+14), wrap once.
    {
      const float4* src = (const float4*)probs;
      const long tb = (long)t * (ROWS * C / 4);   // 1600 f4/tile
      int row = lane / 25, c4 = lane - 25 * (lane / 25);
      #pragma unroll
      for (int k = 0; k < 25; ++k) {
        long q = tb + k * 64 + lane;
        float4 v = (q < totalF4) ? src[q] : make_float4(0.f, 0.f, 0.f, 0.f);
        float* d = &my[row * RSTRIDE + 4 * c4];
        d[0] = v.x; d[1] = v.y; d[2] = v.z; d[3] = v.w;
        row += 2; c4 += 14; if (c4 >= 25) { c4 -= 25; row += 1; }
      }
    }
    // same-wave LDS write->read ordering (DS pipe is FIFO per wave; fence for safety)
    __threadfence_block();

    // ---- compute: lane r owns row r of this wave's tile ----
    const int grow = t * ROWS + lane;
    if (grow < N) {
      const int lab = labels[grow];               // hoisted, coalesced
      const float* rp = &my[lane * RSTRIDE];

      // pass A: max + argmax (first index on ties), 4 independent chains
      float m0 = -INFINITY, m1 = -INFINITY, m2 = -INFINITY, m3 = -INFINITY;
      int   i0 = 0, i1 = 1, i2 = 2, i3 = 3;
      #pragma unroll
      for (int i = 0; i < C; i += 4) {
        float x0 = rp[i], x1 = rp[i + 1], x2 = rp[i + 2], x3 = rp[i + 3];
        if (x0 > m0) { m0 = x0; i0 = i; }
        if (x1 > m1) { m1 = x1; i1 = i + 1; }
        if (x2 > m2) { m2 = x2; i2 = i + 2; }
        if (x3 > m3) { m3 = x3; i3 = i + 3; }
      }
      float M = m0; int idx = i0;
      if (m1 > M || (m1 == M && i1 < idx)) { M = m1; idx = i1; }
      if (m2 > M || (m2 == M && i2 < idx)) { M = m2; idx = i2; }
      if (m3 > M || (m3 == M && i3 < idx)) { M = m3; idx = i3; }

      // pass B: sum exp(x - M), 4 independent chains
      float s0 = 0.f, s1 = 0.f, s2 = 0.f, s3 = 0.f;
      #pragma unroll
      for (int i = 0; i < C; i += 4) {
        s0 += __expf(rp[i]     - M);
        s1 += __expf(rp[i + 1] - M);
        s2 += __expf(rp[i + 2] - M);
        s3 += __expf(rp[i + 3] - M);
      }
      float conf = 1.0f / ((s0 + s1) + (s2 + s3)); // exp(M-M)/sum = 1/sum

      // bin = clip(count(linspace(0,1,16) < conf) - 1, 0, 14)   (exact in R1)
      int cnt = 0;
      #pragma unroll
      for (int i = 0; i <= NBINS; ++i)
        cnt += (((float)i / (float)NBINS) < conf) ? 1 : 0;
      int bin = cnt - 1;
      bin = bin < 0 ? 0 : (bin > NBINS - 1 ? NBINS - 1 : bin);

      atomicAdd(&sbin[bin], conf);
      atomicAdd(&sbin[NBINS + bin], (lab == idx) ? 1.0f : 0.0f);
    }
  }

  __syncthreads();
  // column-major partials: partials[col*G + block], col in [0,30)
  if (threadIdx.x < 2 * NBINS)
    partials[(size_t)threadIdx.x * G + blockIdx.x] = sbin[threadIdx.x];
}

// Pass 2: single block; 32-lane group g reduces column g over G blocks
// (double), then thread 0 computes sum_b |sum_conf_b - sum_corr_b| / N.
__global__ __launch_bounds__(1024) void ece_pass2(
    const float* __restrict__ partials, float* __restrict__ out, int G, int N) {
  __shared__ double cols[32];
  const int lane = threadIdx.x & 31;
  const int grp  = threadIdx.x >> 5;   // 32 groups; 30 used
  double s = 0.0;
  if (grp < 2 * NBINS) {
    for (int g = lane; g < G; g += 32)
      s += (double)partials[(size_t)grp * G + g];
  }
  #pragma unroll
  for (int m = 16; m >= 1; m >>= 1) s += __shfl_xor(s, m);
  if (lane == 0) cols[grp] = s;
  __syncthreads();
  if (threadIdx.x == 0) {
    double e = 0.0;
    for (int b = 0; b < NBINS; ++b) e += fabs(cols[b] - cols[NBINS + b]);
    out[0] = (float)(e / (double)N);
  }
}

extern "C" void kernel_launch(void* const* d_in, const int* in_sizes, int n_in,
                              void* d_out, int out_size, void* d_ws, size_t ws_size,
                              hipStream_t stream) {
  const float* probs    = (const float*)d_in[0];
  const int*   labels   = (const int*)d_in[1];
  float*       out      = (float*)d_out;
  float*       partials = (float*)d_ws;

  const int N = in_sizes[1];            // rows (labels count)

  int G = 768;                          // 3 blocks/CU (LDS 52.9 KB -> 158.6/160 KB)
  size_t need = (size_t)2 * NBINS * G * sizeof(float);
  if (ws_size < need) {
    G = (int)(ws_size / ((size_t)2 * NBINS * sizeof(float)));
    if (G < 1) G = 1;
  }

  ece_pass1<<<G, TPB, 0, stream>>>(probs, labels, partials, N, G);
  ece_pass2<<<1, 1024, 0, stream>>>(partials, out, G, N);
}

// Round 4
// 533.768 us; speedup vs baseline: 1.1228x; 1.1228x over previous
//
#include <hip/hip_runtime.h>
#include <math.h>

#define C 100
#define NBINS 15

// quad_perm DPP: VALU-pipe cross-lane within each 4-lane quad (no DS pipe).
// ctrl 0xB1 = lanes {1,0,3,2} (xor1); 0x4E = {2,3,0,1} (xor2).
#define DPPF(x, ctrl) __int_as_float(__builtin_amdgcn_mov_dpp(__float_as_int(x), (ctrl), 0xF, 0xF, 0))
#define DPPI(x, ctrl) __builtin_amdgcn_mov_dpp((x), (ctrl), 0xF, 0xF, 0)

// Pass 1: one QUAD (4 lanes) per row. Lane l loads float4 k=l+4j (j=0..5),
// all lanes load float4 24 (only lane 0 folds it). Reduction = 2 quad_perm
// DPP stages (VALU) — R1-R3 were DS-pipe-bound on ds_bpermute butterflies /
// scalar LDS traffic; this leaves only 2 LDS atomics/row on the DS pipe.
__global__ __launch_bounds__(256) void ece_pass1(
    const float* __restrict__ probs, const int* __restrict__ labels,
    float* __restrict__ partials, int N, int G) {
  __shared__ float sbin[2 * NBINS];  // [0..14]=sum conf, [15..29]=sum correct
  if (threadIdx.x < 2 * NBINS) sbin[threadIdx.x] = 0.0f;
  __syncthreads();

  const int l   = threadIdx.x & 3;
  const int qid = (blockIdx.x * 256 + threadIdx.x) >> 2;
  const int Q   = G * 64;                     // total quads (256 threads/block)

  for (int row = qid; row < N; row += Q) {
    const float4* rp = (const float4*)(probs + (size_t)row * C);
    float4 v[6];
    #pragma unroll
    for (int j = 0; j < 6; ++j) v[j] = rp[l + 4 * j];   // quad-contiguous 64 B
    float4 t = rp[24];                                  // tail elems 96..99
    const int lab = labels[row];

    // ---- local max + argmax (indices increasing, strict > => first-wins) ----
    float mv = -INFINITY; int mi = 0;
    #pragma unroll
    for (int j = 0; j < 6; ++j) {
      const int b = 4 * l + 16 * j;
      if (v[j].x > mv) { mv = v[j].x; mi = b; }
      if (v[j].y > mv) { mv = v[j].y; mi = b + 1; }
      if (v[j].z > mv) { mv = v[j].z; mi = b + 2; }
      if (v[j].w > mv) { mv = v[j].w; mi = b + 3; }
    }
    if (l == 0) {  // tail indices 96..99 are largest -> processed last, > keeps first
      if (t.x > mv) { mv = t.x; mi = 96; }
      if (t.y > mv) { mv = t.y; mi = 97; }
      if (t.z > mv) { mv = t.z; mi = 98; }
      if (t.w > mv) { mv = t.w; mi = 99; }
    }

    // ---- quad butterfly via DPP (all 4 lanes end with row max/argmax) ----
    {
      float ov = DPPF(mv, 0xB1); int oi = DPPI(mi, 0xB1);
      if (ov > mv || (ov == mv && oi < mi)) { mv = ov; mi = oi; }
    }
    {
      float ov = DPPF(mv, 0x4E); int oi = DPPI(mi, 0x4E);
      if (ov > mv || (ov == mv && oi < mi)) { mv = ov; mi = oi; }
    }

    // ---- sum exp(x - max), 4 independent chains, then quad DPP sum ----
    float s0 = 0.f, s1 = 0.f, s2 = 0.f, s3 = 0.f;
    #pragma unroll
    for (int j = 0; j < 6; ++j) {
      s0 += __expf(v[j].x - mv);
      s1 += __expf(v[j].y - mv);
      s2 += __expf(v[j].z - mv);
      s3 += __expf(v[j].w - mv);
    }
    float se = (s0 + s1) + (s2 + s3);
    if (l == 0)
      se += __expf(t.x - mv) + __expf(t.y - mv) +
            __expf(t.z - mv) + __expf(t.w - mv);
    se += DPPF(se, 0xB1);
    se += DPPF(se, 0x4E);

    // ---- epilogue: quad leader bins + accumulates ----
    if (l == 0) {
      float conf = 1.0f / se;                 // exp(M)/sum exp = 1/sum exp(x-M)
      // bin = clip(count(linspace(0,1,16) < conf) - 1, 0, 14)  (exact in R1)
      int cnt = 0;
      #pragma unroll
      for (int i = 0; i <= NBINS; ++i)
        cnt += (((float)i / (float)NBINS) < conf) ? 1 : 0;
      int bin = cnt - 1;
      bin = bin < 0 ? 0 : (bin > NBINS - 1 ? NBINS - 1 : bin);
      atomicAdd(&sbin[bin], conf);
      atomicAdd(&sbin[NBINS + bin], (lab == mi) ? 1.0f : 0.0f);
    }
  }

  __syncthreads();
  // column-major partials: partials[col*G + block], col in [0,30)
  if (threadIdx.x < 2 * NBINS)
    partials[(size_t)threadIdx.x * G + blockIdx.x] = sbin[threadIdx.x];
}

// Pass 2: single block; 32-lane group g reduces column g over G blocks
// (double), then thread 0 computes sum_b |sum_conf_b - sum_corr_b| / N.
__global__ __launch_bounds__(1024) void ece_pass2(
    const float* __restrict__ partials, float* __restrict__ out, int G, int N) {
  __shared__ double cols[32];
  const int lane = threadIdx.x & 31;
  const int grp  = threadIdx.x >> 5;   // 32 groups; 30 used
  double s = 0.0;
  if (grp < 2 * NBINS) {
    for (int g = lane; g < G; g += 32)
      s += (double)partials[(size_t)grp * G + g];
  }
  #pragma unroll
  for (int m = 16; m >= 1; m >>= 1) s += __shfl_xor(s, m);
  if (lane == 0) cols[grp] = s;
  __syncthreads();
  if (threadIdx.x == 0) {
    double e = 0.0;
    for (int b = 0; b < NBINS; ++b) e += fabs(cols[b] - cols[NBINS + b]);
    out[0] = (float)(e / (double)N);
  }
}

extern "C" void kernel_launch(void* const* d_in, const int* in_sizes, int n_in,
                              void* d_out, int out_size, void* d_ws, size_t ws_size,
                              hipStream_t stream) {
  const float* probs    = (const float*)d_in[0];
  const int*   labels   = (const int*)d_in[1];
  float*       out      = (float*)d_out;
  float*       partials = (float*)d_ws;

  const int N = in_sizes[1];            // rows (labels count)

  int G = 2048;                         // 2048 blocks * 4 waves -> 32 waves/CU
  size_t need = (size_t)2 * NBINS * G * sizeof(float);
  if (ws_size < need) {
    G = (int)(ws_size / ((size_t)2 * NBINS * sizeof(float)));
    if (G < 1) G = 1;
  }

  ece_pass1<<<G, 256, 0, stream>>>(probs, labels, partials, N, G);
  ece_pass2<<<1, 1024, 0, stream>>>(partials, out, G, N);
}